// Round 1
// baseline (305.905 us; speedup 1.0000x reference)
//
#include <hip/hip_runtime.h>

#define PRIME1 2654435761u
#define PRIME2 805459861u
#define PRIME3 3674653429u

// One thread per (point, level). tid = n*16 + l.
// Output: out[n][2*l + f] as one float2 store per thread -> coalesced.
__global__ __launch_bounds__(256) void hash_enc_kernel(
    const float* __restrict__ xyzts,        // [npts,4]
    const float* __restrict__ table,        // [total]
    const int* __restrict__ shapes,         // [16,4]
    const unsigned int* __restrict__ sizes, // [16]
    const int* __restrict__ indicator,      // [16]
    const int* __restrict__ offsets,        // [16]
    float* __restrict__ out,                // [npts,32]
    int npts)
{
    int tid = blockIdx.x * 256 + threadIdx.x;
    int n = tid >> 4;
    if (n >= npts) return;
    int l = tid & 15;

    // 16 lanes share the same point -> same-address broadcast from L1.
    float4 x = reinterpret_cast<const float4*>(xyzts)[n];
    int4 rs = reinterpret_cast<const int4*>(shapes)[l];
    unsigned int size = sizes[l];
    unsigned int msk = size - 1u;          // valid: indicator==0 => size == 2^19
    bool ind = (indicator[l] != 0);
    int off = offsets[l];

    // pos = x * resf; grid = clip(floor(pos), 0, res-1); frac = clip(pos-grid, 0, 1)
    // Plain mul/sub, floorf, fmin/fmax to match the JAX fp32 computation bit-exactly.
    float r0 = (float)rs.x, r1 = (float)rs.y, r2 = (float)rs.z, r3 = (float)rs.w;
    float p0 = x.x * r0, p1 = x.y * r1, p2 = x.z * r2, p3 = x.w * r3;
    float g0 = fminf(fmaxf(floorf(p0), 0.f), r0 - 1.f);
    float g1 = fminf(fmaxf(floorf(p1), 0.f), r1 - 1.f);
    float g2 = fminf(fmaxf(floorf(p2), 0.f), r2 - 1.f);
    float g3 = fminf(fmaxf(floorf(p3), 0.f), r3 - 1.f);
    float f0 = fminf(fmaxf(p0 - g0, 0.f), 1.f);
    float f1 = fminf(fmaxf(p1 - g1, 0.f), 1.f);
    float f2 = fminf(fmaxf(p2 - g2, 0.f), 1.f);
    float f3 = fminf(fmaxf(p3 - g3, 0.f), 1.f);
    unsigned int u0 = (unsigned int)g0, u1 = (unsigned int)g1;
    unsigned int u2 = (unsigned int)g2, u3 = (unsigned int)g3;

    // strides (uint32 wrap-around semantics match jnp.uint32)
    unsigned int s1 = (unsigned int)(rs.x + 1);
    unsigned int s2 = s1 * (unsigned int)(rs.y + 1);
    unsigned int s3 = s2 * (unsigned int)(rs.z + 1);

    // fast-hash base + per-dim XOR deltas: selecting bit d toggles e_d
    unsigned int a1 = u1 * PRIME1, a2 = u2 * PRIME2, a3 = u3 * PRIME3;
    unsigned int xb = u0 ^ a1 ^ a2 ^ a3;
    unsigned int e0 = u0 ^ (u0 + 1u);
    unsigned int e1 = a1 ^ ((u1 + 1u) * PRIME1);
    unsigned int e2 = a2 ^ ((u2 + 1u) * PRIME2);
    unsigned int e3 = a3 ^ ((u3 + 1u) * PRIME3);

    // under-hash base; selecting bit d adds stride_d. under < raw <= size when ind==1.
    unsigned int ab = u0 + u1 * s1 + u2 * s2 + u3 * s3;

    float om0 = 1.f - f0, om1 = 1.f - f1, om2 = 1.f - f2, om3 = 1.f - f3;

    const float* tb = table + off;

    float acc0 = 0.f, acc1 = 0.f;
#pragma unroll
    for (int c = 0; c < 16; ++c) {
        unsigned int hf = xb, hu = ab;
        if (c & 1) { hf ^= e0; hu += 1u; }
        if (c & 2) { hf ^= e1; hu += s1; }
        if (c & 4) { hf ^= e2; hu += s2; }
        if (c & 8) { hf ^= e3; hu += s3; }
        unsigned int h = ind ? hu : (hf & msk);
        float2 tv = *reinterpret_cast<const float2*>(tb + 2u * h);
        // weight product in the reference's d0->d3 order
        float w = (c & 1) ? f0 : om0;
        w *= (c & 2) ? f1 : om1;
        w *= (c & 4) ? f2 : om2;
        w *= (c & 8) ? f3 : om3;
        acc0 += w * tv.x;
        acc1 += w * tv.y;
    }

    reinterpret_cast<float2*>(out)[n * 16 + l] = make_float2(acc0, acc1);
}

extern "C" void kernel_launch(void* const* d_in, const int* in_sizes, int n_in,
                              void* d_out, int out_size, void* d_ws, size_t ws_size,
                              hipStream_t stream) {
    const float* xyzts = (const float*)d_in[0];
    const float* table = (const float*)d_in[1];
    const int* shapes = (const int*)d_in[2];
    const unsigned int* sizes = (const unsigned int*)d_in[3];
    const int* indicator = (const int*)d_in[4];
    const int* offsets = (const int*)d_in[5];
    float* out = (float*)d_out;

    int npts = in_sizes[0] / 4;
    int total = npts * 16;
    int blocks = (total + 255) / 256;
    hash_enc_kernel<<<blocks, 256, 0, stream>>>(xyzts, table, shapes, sizes,
                                                indicator, offsets, out, npts);
}

// Round 2
// 132.673 us; speedup vs baseline: 2.3057x; 2.3057x over previous
//
#include <hip/hip_runtime.h>

#define PRIME1 2654435761u
#define PRIME2 805459861u
#define PRIME3 3674653429u

// Level-major mapping: each block = 256 points x ONE level.
// Grid = nchunks*16 blocks. Mapping chosen so that (blockIdx % 8) == (level % 8)
// and the first half of the grid covers levels 0..7, second half 8..15.
// With round-robin blockIdx->XCD dispatch, XCD k then works on a single ~4MB
// level table at a time -> table stays resident in that XCD's 4MB L2.
__global__ __launch_bounds__(256) void hash_enc_kernel(
    const float* __restrict__ xyzts,        // [npts,4]
    const float* __restrict__ table,        // [total]
    const int* __restrict__ shapes,         // [16,4]
    const unsigned int* __restrict__ sizes, // [16]
    const int* __restrict__ indicator,      // [16]
    const int* __restrict__ offsets,        // [16]
    float* __restrict__ out,                // [npts,32]
    int npts, int nchunks)
{
    int b = blockIdx.x;
    int half = b / (nchunks * 8);       // 0 -> levels 0..7, 1 -> levels 8..15
    int within = b % (nchunks * 8);
    int level = (within & 7) + (half << 3);   // uniform: depends only on blockIdx
    int chunk = within >> 3;
    int n = chunk * 256 + (int)threadIdx.x;
    if (n >= npts) return;

    // level is wave-uniform -> these become scalar loads
    int4 rs = reinterpret_cast<const int4*>(shapes)[level];
    unsigned int size = sizes[level];
    unsigned int msk = size - 1u;       // indicator==0 => size == 2^19 (pow2)
    bool ind = (indicator[level] != 0);
    int off = offsets[level];

    // coalesced 16B/lane point load
    float4 x = reinterpret_cast<const float4*>(xyzts)[n];

    // pos = x*resf; grid = clip(floor(pos),0,res-1); frac = clip(pos-grid,0,1)
    float r0 = (float)rs.x, r1 = (float)rs.y, r2 = (float)rs.z, r3 = (float)rs.w;
    float p0 = x.x * r0, p1 = x.y * r1, p2 = x.z * r2, p3 = x.w * r3;
    float g0 = fminf(fmaxf(floorf(p0), 0.f), r0 - 1.f);
    float g1 = fminf(fmaxf(floorf(p1), 0.f), r1 - 1.f);
    float g2 = fminf(fmaxf(floorf(p2), 0.f), r2 - 1.f);
    float g3 = fminf(fmaxf(floorf(p3), 0.f), r3 - 1.f);
    float f0 = fminf(fmaxf(p0 - g0, 0.f), 1.f);
    float f1 = fminf(fmaxf(p1 - g1, 0.f), 1.f);
    float f2 = fminf(fmaxf(p2 - g2, 0.f), 1.f);
    float f3 = fminf(fmaxf(p3 - g3, 0.f), 1.f);
    unsigned int u0 = (unsigned int)g0, u1 = (unsigned int)g1;
    unsigned int u2 = (unsigned int)g2, u3 = (unsigned int)g3;

    // strides (uint32 wrap semantics)
    unsigned int s1 = (unsigned int)(rs.x + 1);
    unsigned int s2 = s1 * (unsigned int)(rs.y + 1);
    unsigned int s3 = s2 * (unsigned int)(rs.z + 1);

    // fast-hash base + per-dim XOR deltas
    unsigned int a1 = u1 * PRIME1, a2 = u2 * PRIME2, a3 = u3 * PRIME3;
    unsigned int xb = u0 ^ a1 ^ a2 ^ a3;
    unsigned int e0 = u0 ^ (u0 + 1u);
    unsigned int e1 = a1 ^ ((u1 + 1u) * PRIME1);
    unsigned int e2 = a2 ^ ((u2 + 1u) * PRIME2);
    unsigned int e3 = a3 ^ ((u3 + 1u) * PRIME3);

    // under-hash base; under < raw <= size when ind==1 -> no mod needed
    unsigned int ab = u0 + u1 * s1 + u2 * s2 + u3 * s3;

    float om0 = 1.f - f0, om1 = 1.f - f1, om2 = 1.f - f2, om3 = 1.f - f3;

    const float* tb = table + off;

    float acc0 = 0.f, acc1 = 0.f;
#pragma unroll
    for (int c = 0; c < 16; ++c) {
        unsigned int hf = xb, hu = ab;
        if (c & 1) { hf ^= e0; hu += 1u; }
        if (c & 2) { hf ^= e1; hu += s1; }
        if (c & 4) { hf ^= e2; hu += s2; }
        if (c & 8) { hf ^= e3; hu += s3; }
        unsigned int h = ind ? hu : (hf & msk);
        float2 tv = *reinterpret_cast<const float2*>(tb + 2u * h);
        float w = (c & 1) ? f0 : om0;
        w *= (c & 2) ? f1 : om1;
        w *= (c & 4) ? f2 : om2;
        w *= (c & 8) ? f3 : om3;
        acc0 += w * tv.x;
        acc1 += w * tv.y;
    }

    // 8B per lane at 128B stride; L2 merges partial lines across levels.
    reinterpret_cast<float2*>(out)[n * 16 + level] = make_float2(acc0, acc1);
}

extern "C" void kernel_launch(void* const* d_in, const int* in_sizes, int n_in,
                              void* d_out, int out_size, void* d_ws, size_t ws_size,
                              hipStream_t stream) {
    const float* xyzts = (const float*)d_in[0];
    const float* table = (const float*)d_in[1];
    const int* shapes = (const int*)d_in[2];
    const unsigned int* sizes = (const unsigned int*)d_in[3];
    const int* indicator = (const int*)d_in[4];
    const int* offsets = (const int*)d_in[5];
    float* out = (float*)d_out;

    int npts = in_sizes[0] / 4;
    int nchunks = (npts + 255) / 256;
    int blocks = nchunks * 16;
    hash_enc_kernel<<<blocks, 256, 0, stream>>>(xyzts, table, shapes, sizes,
                                                indicator, offsets, out,
                                                npts, nchunks);
}